// Round 1
// 1888.438 us; speedup vs baseline: 1.0420x; 1.0420x over previous
//
#include <hip/hip_runtime.h>

typedef __bf16 bf16x8 __attribute__((ext_vector_type(8)));
typedef float f32x4 __attribute__((ext_vector_type(4)));
typedef unsigned short u16;
typedef unsigned int u32;

#define D_DIM 4096
#define B_ROWS 16384
#define K_CLS 14
#define M_TOT 32768

// ---------- helpers ----------
__device__ __forceinline__ u32 f2bf(float f) {
    u32 u = __float_as_uint(f);
    return (u + 0x7FFFu + ((u >> 16) & 1u)) >> 16;   // RNE
}
__device__ __forceinline__ float bfl(u32 u) { return __uint_as_float(u << 16); }
__device__ __forceinline__ float bfh(u32 u) { return __uint_as_float(u & 0xFFFF0000u); }

typedef __attribute__((address_space(3))) void lds_void;
typedef __attribute__((address_space(1))) void glb_void;

// async global->LDS, 16B per lane; LDS dest = wave-uniform base + lane*16
__device__ __forceinline__ void g2lds16(const void* g, void* l) {
    __builtin_amdgcn_global_load_lds(
        reinterpret_cast<glb_void*>(reinterpret_cast<uintptr_t>(g)),
        reinterpret_cast<lds_void*>(reinterpret_cast<uintptr_t>(l)),
        16, 0, 0);
}

// ---------- cast f32 -> bf16 (4 elems/thread) ----------
__global__ void cast_bf16(const float* __restrict__ src, u16* __restrict__ dst, int n4) {
    int i = blockIdx.x * blockDim.x + threadIdx.x;
    int stride = gridDim.x * blockDim.x;
    for (; i < n4; i += stride) {
        float4 a = ((const float4*)src)[i];
        uint2 o;
        o.x = f2bf(a.x) | (f2bf(a.y) << 16);
        o.y = f2bf(a.z) | (f2bf(a.w) << 16);
        ((uint2*)dst)[i] = o;
    }
}

// ---------- prototype normalize + passthrough copy ----------
__global__ void proto_norm(const float* __restrict__ P, u16* __restrict__ pTbf,
                           float* __restrict__ outProto) {
    const int k = blockIdx.x;
    const int tid = threadIdx.x;
    float ss = 0.f;
    for (int d = tid; d < D_DIM; d += 256) {
        float v = P[k * D_DIM + d];
        ss += v * v;
    }
    for (int off = 32; off; off >>= 1) ss += __shfl_down(ss, off);
    __shared__ float red[4];
    if ((tid & 63) == 0) red[tid >> 6] = ss;
    __syncthreads();
    float tot = red[0] + red[1] + red[2] + red[3];
    float inv = 1.0f / fmaxf(sqrtf(tot), 1e-12f);
    for (int d = tid; d < D_DIM; d += 256) {
        float v = P[k * D_DIM + d];
        outProto[k * D_DIM + d] = v;                       // exact passthrough
        pTbf[(size_t)d * 16 + k] = (u16)f2bf(v * inv);
    }
}

// ---------- batch co-occurrence ----------
__global__ void cooccur_bc(const int* __restrict__ L, float* __restrict__ bc) {
    const int i = blockIdx.x / K_CLS, j = blockIdx.x % K_CLS;
    int s = 0;
    for (int b = threadIdx.x; b < B_ROWS; b += 256)
        s += L[b * K_CLS + i] * L[b * K_CLS + j];
    for (int off = 32; off; off >>= 1) s += __shfl_down(s, off);
    __shared__ int red[4];
    if ((threadIdx.x & 63) == 0) red[threadIdx.x >> 6] = s;
    __syncthreads();
    if (threadIdx.x == 0)
        bc[blockIdx.x] = (float)(red[0] + red[1] + red[2] + red[3]) / (float)B_ROWS;
}

__global__ void cooccur_loss(const float* __restrict__ C, const float* __restrict__ bc,
                             float* __restrict__ out) {
    const int t = threadIdx.x;
    float d2 = 0.f;
    if (t < K_CLS * K_CLS) {
        float s = 1.0f / (1.0f + expf(-C[t]));
        float d = s - bc[t];
        d2 = d * d;
    }
    for (int off = 32; off; off >>= 1) d2 += __shfl_down(d2, off);
    __shared__ float red[4];
    if ((t & 63) == 0) red[t >> 6] = d2;
    __syncthreads();
    if (t == 0) out[0] = (red[0] + red[1] + red[2] + red[3]) / (float)(K_CLS * K_CLS);
}

// ---------- bf16 GEMM-BT, 256x256 tile, BK=64, 8 waves, 4-phase counted-vmcnt ----------
// 256^2 8-phase-template port: T2 XOR-swizzle (slot^row&7, conflict-free ds_read_b128),
// T3/T4 phase split with vmcnt(8) (never 0 in main loop), T5 setprio around MFMA,
// T1 XCD-contiguous block swizzle. LDS 128 KiB (1 block/CU, 2 waves/SIMD by design).
#define BK 64
#define NKT (D_DIM / BK)          // 64 K-tiles
#define TILE_E (256 * 64)         // u16 elems per tile buffer (32 KB)

// staging: 8 global_load_lds per thread per K-tile (A 4 + B 4).
// LDS dest linear; global SOURCE pre-swizzled with the same involution the
// readers apply (rule 21): stored phys slot s' holds global slot s'^(row&7).
#define STAGE(ABUF, BBUF, k0) do {                                             \
    _Pragma("unroll")                                                          \
    for (int i_ = 0; i_ < 4; i_++)                                             \
        g2lds16(Apan + gOff[i_] + (k0), (ABUF) + lOff[i_]);                    \
    _Pragma("unroll")                                                          \
    for (int i_ = 0; i_ < 4; i_++)                                             \
        g2lds16(Bpan + gOff[i_] + (k0), (BBUF) + lOff[i_]);                    \
} while (0)

#define LOAD_B(BBUF) do {                                                      \
    _Pragma("unroll")                                                          \
    for (int ni_ = 0; ni_ < 4; ni_++) {                                        \
        bfr[ni_][0] = *(const bf16x8*)((BBUF) + bBase + ni_ * 16 * BK + so0);  \
        bfr[ni_][1] = *(const bf16x8*)((BBUF) + bBase + ni_ * 16 * BK + so1);  \
    }                                                                          \
} while (0)

#define LOAD_A(ABUF, q) do {                                                   \
    _Pragma("unroll")                                                          \
    for (int s_ = 0; s_ < 2; s_++) {                                           \
        afr[s_][0] = *(const bf16x8*)((ABUF) + aBase + ((q) * 32 + s_ * 16) * BK + so0); \
        afr[s_][1] = *(const bf16x8*)((ABUF) + aBase + ((q) * 32 + s_ * 16) * BK + so1); \
    }                                                                          \
} while (0)

#define MFMA_PHASE(q) do {                                                     \
    __builtin_amdgcn_s_setprio(1);                                             \
    _Pragma("unroll")                                                          \
    for (int s_ = 0; s_ < 2; s_++)                                             \
    _Pragma("unroll")                                                          \
    for (int ni_ = 0; ni_ < 4; ni_++) {                                        \
        acc[(q) * 2 + s_][ni_] = __builtin_amdgcn_mfma_f32_16x16x32_bf16(      \
            afr[s_][0], bfr[ni_][0], acc[(q) * 2 + s_][ni_], 0, 0, 0);         \
        acc[(q) * 2 + s_][ni_] = __builtin_amdgcn_mfma_f32_16x16x32_bf16(      \
            afr[s_][1], bfr[ni_][1], acc[(q) * 2 + s_][ni_], 0, 0, 0);         \
    }                                                                          \
    __builtin_amdgcn_s_setprio(0);                                             \
} while (0)

// phase: reads -> barrier -> lgkmcnt(0) (+sched_barrier, rule 18) -> MFMA -> barrier
#define PHASE0(ABUF, BBUF) do { LOAD_B(BBUF); LOAD_A(ABUF, 0);                 \
    __builtin_amdgcn_s_barrier();                                              \
    asm volatile("s_waitcnt lgkmcnt(0)" ::: "memory");                         \
    __builtin_amdgcn_sched_barrier(0);                                         \
    MFMA_PHASE(0);                                                             \
    __builtin_amdgcn_s_barrier(); } while (0)

#define PHASEQ(ABUF, q) do { LOAD_A(ABUF, q);                                  \
    __builtin_amdgcn_s_barrier();                                              \
    asm volatile("s_waitcnt lgkmcnt(0)" ::: "memory");                         \
    __builtin_amdgcn_sched_barrier(0);                                         \
    MFMA_PHASE(q);                                                             \
    __builtin_amdgcn_s_barrier(); } while (0)

// body: 4 quadrant phases on buffer p, then stage tile t+2 into p (safe: all
// reads of p completed behind the phase-3 end barrier), wait vmcnt(8) so tile
// t+1 (issued one body ago) has landed, barrier. Never vmcnt(0) mid-loop.
#define TILE_BODY(ABUF, BBUF, t) do {                                          \
    bf16x8 bfr[4][2], afr[2][2];                                               \
    PHASE0(ABUF, BBUF);                                                        \
    PHASEQ(ABUF, 1);                                                           \
    PHASEQ(ABUF, 2);                                                           \
    PHASEQ(ABUF, 3);                                                           \
    __builtin_amdgcn_sched_barrier(0);                                         \
    if ((t) + 2 < NKT) {                                                       \
        STAGE(ABUF, BBUF, ((t) + 2) * BK);                                     \
        asm volatile("s_waitcnt vmcnt(8)" ::: "memory");                       \
    } else if ((t) + 1 < NKT) {                                                \
        asm volatile("s_waitcnt vmcnt(0)" ::: "memory");                       \
    }                                                                          \
    __builtin_amdgcn_sched_barrier(0);                                         \
    __builtin_amdgcn_s_barrier();                                              \
} while (0)

__global__ __launch_bounds__(512, 2) void gemm_bt(
    const u16* __restrict__ Xbf,   // [32768][4096]
    const u16* __restrict__ Wbf,   // [2][4096][4096]
    const float* __restrict__ bv, const float* __restrict__ bt,
    u16* __restrict__ Ybf)         // [32768][4096]
{
    __shared__ __align__(16) u16 lds[4 * TILE_E];   // 128 KB: A0,A1,B0,B1
    u16* const As0 = lds;
    u16* const As1 = lds + TILE_E;
    u16* const Bs0 = lds + 2 * TILE_E;
    u16* const Bs1 = lds + 3 * TILE_E;

    const int tid = threadIdx.x;
    const int wave = tid >> 6, lane = tid & 63;

    // XCD-contiguous bijective swizzle (nwg=2048, %8==0)
    const int bid = blockIdx.x;
    const int swzb = (bid & 7) * 256 + (bid >> 3);
    const int bn0 = (swzb & 15) * 256;      // 16 col-blocks
    const int bm0 = (swzb >> 4) * 256;      // 128 row-blocks
    const int half = (bm0 >= B_ROWS) ? 1 : 0;
    const u16* __restrict__ Apan = Xbf + (size_t)bm0 * D_DIM;
    const u16* __restrict__ Bpan = Wbf + (size_t)half * D_DIM * D_DIM
                                       + (size_t)bn0 * D_DIM;
    const float* bias = half ? bt : bv;

    // staging addresses: chunk c = 8 rows x 64 cols (1 KB); wave owns chunks
    // 4w..4w+3 of A and of B. row&7 == lane>>3 (chunks 8-row aligned), so the
    // pre-swizzled source slot is (lane&7)^(lane>>3) -- constant per lane.
    const int lrow = lane >> 3;
    const int lslot = ((lane & 7) ^ lrow) * 8;       // elems
    size_t gOff[4];
    int lOff[4];
#pragma unroll
    for (int i = 0; i < 4; i++) {
        const int c = wave * 4 + i;
        gOff[i] = (size_t)(c * 8 + lrow) * D_DIM + lslot;
        lOff[i] = c * 512;                            // elems (c*1024 B)
    }

    // reader fragment addressing; fragment row&7 == lane&7 for all rows, so
    // the read-side XOR is a per-lane constant too.
    const int wm = wave >> 2, wn = wave & 3;
    const int mlane = lane & 15, quad = lane >> 4;
    const int lswz = lane & 7;
    const int so0 = (quad ^ lswz) * 8;               // ks=0 slot (elems)
    const int so1 = ((4 + quad) ^ lswz) * 8;         // ks=1 slot
    const int aBase = (wm * 128 + mlane) * BK;
    const int bBase = (wn * 64 + mlane) * BK;

    f32x4 acc[8][4] = {};

    // prologue: stage tiles 0 and 1, wait tile 0 (vmcnt(8): 8 newest in flight)
    STAGE(As0, Bs0, 0);
    STAGE(As1, Bs1, BK);
    asm volatile("s_waitcnt vmcnt(8)" ::: "memory");
    __builtin_amdgcn_sched_barrier(0);
    __builtin_amdgcn_s_barrier();

    for (int tt = 0; tt < NKT; tt += 2) {
        TILE_BODY(As0, Bs0, tt);
        TILE_BODY(As1, Bs1, tt + 1);
    }

    // epilogue: C/D layout col=lane&15, row=quad*4+reg
#pragma unroll
    for (int ni = 0; ni < 4; ni++) {
        const int col = bn0 + wn * 64 + ni * 16 + mlane;
        const float bcol = bias[col];
#pragma unroll
        for (int mi = 0; mi < 8; mi++) {
            f32x4 v = acc[mi][ni];
            const size_t rb = (size_t)(bm0 + wm * 128 + mi * 16 + quad * 4) * D_DIM + col;
#pragma unroll
            for (int r = 0; r < 4; r++)
                Ybf[rb + (size_t)r * D_DIM] = (u16)f2bf(v[r] + bcol);
        }
    }
}

// ---------- sim + norm + finalize (fused): one wave = 2 img rows + 2 txt rows ----------
__global__ __launch_bounds__(256) void simproj(
    const u16* __restrict__ Ybf, const u16* __restrict__ pTbf,
    const int* __restrict__ L, float* __restrict__ out)
{
    const int tid = threadIdx.x;
    const int wave = tid >> 6, lane = tid & 63;
    const int r0 = blockIdx.x * 8 + wave * 2;        // img rows r0, r0+1
    const u16* Yi = Ybf + (size_t)r0 * D_DIM;
    const u16* Yt = Yi + (size_t)B_ROWS * D_DIM;     // matching text rows

    float acc[4][15];
#pragma unroll
    for (int r = 0; r < 4; r++)
#pragma unroll
        for (int k = 0; k < 15; k++) acc[r][k] = 0.f;

#pragma unroll 2
    for (int i = 0; i < 64; i++) {
        const int d = lane + i * 64;
        const uint4* pq = (const uint4*)(pTbf + (size_t)d * 16);
        const uint4 q0 = pq[0], q1 = pq[1];
        const float p[14] = { bfl(q0.x), bfh(q0.x), bfl(q0.y), bfh(q0.y),
                              bfl(q0.z), bfh(q0.z), bfl(q0.w), bfh(q0.w),
                              bfl(q1.x), bfh(q1.x), bfl(q1.y), bfh(q1.y),
                              bfl(q1.z), bfh(q1.z) };
        float yv[4];
        yv[0] = bfl((u32)Yi[d]);
        yv[1] = bfl((u32)Yi[D_DIM + d]);
        yv[2] = bfl((u32)Yt[d]);
        yv[3] = bfl((u32)Yt[D_DIM + d]);
#pragma unroll
        for (int r = 0; r < 4; r++) {
            acc[r][14] += yv[r] * yv[r];
#pragma unroll
            for (int k = 0; k < 14; k++) acc[r][k] += yv[r] * p[k];
        }
    }
#pragma unroll
    for (int r = 0; r < 4; r++)
#pragma unroll
        for (int k = 0; k < 15; k++) {
            float v = acc[r][k];
            v += __shfl_xor(v, 1);  v += __shfl_xor(v, 2);  v += __shfl_xor(v, 4);
            v += __shfl_xor(v, 8);  v += __shfl_xor(v, 16); v += __shfl_xor(v, 32);
            acc[r][k] = v;
        }
    if (lane == 0) {
#pragma unroll
        for (int rr = 0; rr < 2; rr++) {
            const float iv = 1.0f / fmaxf(sqrtf(acc[rr][14]), 1e-12f);
            const float it = 1.0f / fmaxf(sqrtf(acc[2 + rr][14]), 1e-12f);
#pragma unroll
            for (int k = 0; k < 14; k++) {
                const int idx = (r0 + rr) * K_CLS + k;
                out[idx] = 0.5f * (acc[rr][k] * iv + acc[2 + rr][k] * it)
                           * (float)L[idx];
            }
        }
    }
}

// ---------- launch ----------
extern "C" void kernel_launch(void* const* d_in, const int* in_sizes, int n_in,
                              void* d_out, int out_size, void* d_ws, size_t ws_size,
                              hipStream_t stream) {
    const float* image  = (const float*)d_in[0];
    const float* text   = (const float*)d_in[1];
    const int*   labels = (const int*)d_in[2];
    const float* Wv     = (const float*)d_in[3];
    const float* bv     = (const float*)d_in[4];
    const float* Wt     = (const float*)d_in[5];
    const float* bt     = (const float*)d_in[6];
    const float* protos = (const float*)d_in[7];
    const float* cooc   = (const float*)d_in[8];
    float* out = (float*)d_out;

    // workspace layout (bytes)
    const size_t OFF_X   = 0;                       // 268,435,456  x bf16 [32768][4096]
    const size_t OFF_W   = 268435456ull;            //  67,108,864  Wv,Wt bf16
    const size_t OFF_Y   = 335544320ull;            // 268,435,456  y bf16 [32768][4096]
    const size_t OFF_PT  = 603979776ull;            //     131,072  p_hat bf16 [4096][16]
    const size_t OFF_SIM = 604110848ull;            //   (unused now, kept for layout)
    const size_t OFF_BC  = 605945856ull;            //         784  bc f32 [196]
    const size_t NEED    = 605946640ull;
    if (ws_size < NEED) return;
    (void)OFF_SIM;

    char* ws = (char*)d_ws;
    u16*   Xbf  = (u16*)(ws + OFF_X);
    u16*   Wbf  = (u16*)(ws + OFF_W);
    u16*   Ybf  = (u16*)(ws + OFF_Y);
    u16*   pTbf = (u16*)(ws + OFF_PT);
    float* bc   = (float*)(ws + OFF_BC);

    // casts
    cast_bf16<<<4096, 256, 0, stream>>>(image, Xbf, (B_ROWS * D_DIM) / 4);
    cast_bf16<<<4096, 256, 0, stream>>>(text, Xbf + (size_t)B_ROWS * D_DIM, (B_ROWS * D_DIM) / 4);
    cast_bf16<<<2048, 256, 0, stream>>>(Wv, Wbf, (D_DIM * D_DIM) / 4);
    cast_bf16<<<2048, 256, 0, stream>>>(Wt, Wbf + (size_t)D_DIM * D_DIM, (D_DIM * D_DIM) / 4);

    // small side computations
    proto_norm<<<K_CLS, 256, 0, stream>>>(protos, pTbf, out + B_ROWS * K_CLS);
    cooccur_bc<<<K_CLS * K_CLS, 256, 0, stream>>>(labels, bc);
    cooccur_loss<<<1, 256, 0, stream>>>(cooc, bc, out + B_ROWS * K_CLS + K_CLS * D_DIM);

    // main GEMM: 2048 blocks of 512 threads; 256x256 tiles over [32768][4096]
    gemm_bt<<<(M_TOT / 256) * (D_DIM / 256), 512, 0, stream>>>(Xbf, Wbf, bv, bt, Ybf);

    // projection + normalization + shapley combine (fused)
    simproj<<<B_ROWS / 8, 256, 0, stream>>>(Ybf, pTbf, labels, out);
}

// Round 2
// 1832.295 us; speedup vs baseline: 1.0739x; 1.0306x over previous
//
#include <hip/hip_runtime.h>

typedef __bf16 bf16x8 __attribute__((ext_vector_type(8)));
typedef float f32x4 __attribute__((ext_vector_type(4)));
typedef unsigned short u16;
typedef unsigned int u32;

#define D_DIM 4096
#define B_ROWS 16384
#define K_CLS 14
#define M_TOT 32768

// ---------- helpers ----------
__device__ __forceinline__ u32 f2bf(float f) {
    u32 u = __float_as_uint(f);
    return (u + 0x7FFFu + ((u >> 16) & 1u)) >> 16;   // RNE
}
__device__ __forceinline__ float bfl(u32 u) { return __uint_as_float(u << 16); }
__device__ __forceinline__ float bfh(u32 u) { return __uint_as_float(u & 0xFFFF0000u); }

typedef __attribute__((address_space(3))) void lds_void;
typedef __attribute__((address_space(1))) void glb_void;

__device__ __forceinline__ void g2lds16(const void* g, void* l) {
    __builtin_amdgcn_global_load_lds(
        reinterpret_cast<glb_void*>(reinterpret_cast<uintptr_t>(g)),
        reinterpret_cast<lds_void*>(reinterpret_cast<uintptr_t>(l)),
        16, 0, 0);
}

// ---------- fused cast f32 -> bf16 for all four inputs ----------
__global__ void cast_all(const float* __restrict__ im, const float* __restrict__ tx,
                         const float* __restrict__ wv, const float* __restrict__ wt,
                         u16* __restrict__ Xbf, u16* __restrict__ Wbf) {
    const int nX = (B_ROWS * D_DIM) / 4;   // float4 units per X half
    const int nW = (D_DIM * D_DIM) / 4;
    const int total = 2 * nX + 2 * nW;
    int i = blockIdx.x * blockDim.x + threadIdx.x;
    const int stride = gridDim.x * blockDim.x;
    for (; i < total; i += stride) {
        const float* s; u16* d; int off;
        if (i < nX)               { s = im; d = Xbf;                       off = i; }
        else if (i < 2 * nX)      { s = tx; d = Xbf + (size_t)nX * 4;      off = i - nX; }
        else if (i < 2 * nX + nW) { s = wv; d = Wbf;                       off = i - 2 * nX; }
        else                      { s = wt; d = Wbf + (size_t)nW * 4;      off = i - 2 * nX - nW; }
        float4 a = ((const float4*)s)[off];
        uint2 o;
        o.x = f2bf(a.x) | (f2bf(a.y) << 16);
        o.y = f2bf(a.z) | (f2bf(a.w) << 16);
        ((uint2*)d)[off] = o;
    }
}

// ---------- prototype normalize + passthrough copy ----------
__global__ void proto_norm(const float* __restrict__ P, u16* __restrict__ pTbf,
                           float* __restrict__ outProto) {
    const int k = blockIdx.x;
    const int tid = threadIdx.x;
    float ss = 0.f;
    for (int d = tid; d < D_DIM; d += 256) {
        float v = P[k * D_DIM + d];
        ss += v * v;
    }
    for (int off = 32; off; off >>= 1) ss += __shfl_down(ss, off);
    __shared__ float red[4];
    if ((tid & 63) == 0) red[tid >> 6] = ss;
    __syncthreads();
    float tot = red[0] + red[1] + red[2] + red[3];
    float inv = 1.0f / fmaxf(sqrtf(tot), 1e-12f);
    for (int d = tid; d < D_DIM; d += 256) {
        float v = P[k * D_DIM + d];
        outProto[k * D_DIM + d] = v;                       // exact passthrough
        pTbf[(size_t)d * 16 + k] = (u16)f2bf(v * inv);
    }
}

// ---------- batch co-occurrence ----------
__global__ void cooccur_bc(const int* __restrict__ L, float* __restrict__ bc) {
    const int i = blockIdx.x / K_CLS, j = blockIdx.x % K_CLS;
    int s = 0;
    for (int b = threadIdx.x; b < B_ROWS; b += 256)
        s += L[b * K_CLS + i] * L[b * K_CLS + j];
    for (int off = 32; off; off >>= 1) s += __shfl_down(s, off);
    __shared__ int red[4];
    if ((threadIdx.x & 63) == 0) red[threadIdx.x >> 6] = s;
    __syncthreads();
    if (threadIdx.x == 0)
        bc[blockIdx.x] = (float)(red[0] + red[1] + red[2] + red[3]) / (float)B_ROWS;
}

__global__ void cooccur_loss(const float* __restrict__ C, const float* __restrict__ bc,
                             float* __restrict__ out) {
    const int t = threadIdx.x;
    float d2 = 0.f;
    if (t < K_CLS * K_CLS) {
        float s = 1.0f / (1.0f + expf(-C[t]));
        float d = s - bc[t];
        d2 = d * d;
    }
    for (int off = 32; off; off >>= 1) d2 += __shfl_down(d2, off);
    __shared__ float red[4];
    if ((t & 63) == 0) red[t >> 6] = d2;
    __syncthreads();
    if (t == 0) out[0] = (red[0] + red[1] + red[2] + red[3]) / (float)(K_CLS * K_CLS);
}

// ---------- bf16 GEMM-BT, 256x256 tile, BK=64, 8 waves, true 8-phase schedule ----------
// Per-phase: {4-12 ds_read_b128 || stage 1 half-tile (2 global_load_lds)} ->
// barrier -> lgkmcnt(0)+sched_barrier -> setprio(1) 16 MFMA setprio(0) -> barrier.
// vmcnt(2) only at phases 4 and 8. M-interleaved reads open per-half WAR windows:
//   A-half0 read p1-2, A-half1 p3-4, B halves p1-4 (per buffer).
// Stage slots (iter reads tile t in buf0 @p1-4, t+1 in buf1 @p5-8):
//   p1: buf1.A1(t+1)  p2: buf1.B0(t+1)  p3: buf1.B1(t+1)  p4: buf0.A0(t+2) [w]
//   p5: buf0.A1(t+2)  p6: buf0.B0(t+2)  p7: buf0.B1(t+2)  p8: buf1.A0(t+3) [w]
// Tail iterations issue harmless in-bounds dummy stages (uniform vmcnt counts).
#define BK 64
#define NKT (D_DIM / BK)          // 64 K-tiles
#define TILE_E (256 * 64)         // u16 elems per tile buffer (32 KB)

// stage one half-tile: 16 chunks of 8 rows x 64 cols; wave stages chunks wave*2+{0,1}
#define STAGE_HALF(DST, PAN, k0, h) do {                                       \
    _Pragma("unroll")                                                          \
    for (int i_ = 0; i_ < 2; i_++) {                                           \
        const int c_ = (h) * 16 + wave * 2 + i_;                               \
        g2lds16((PAN) + (size_t)(c_ * 8 + lrow) * D_DIM + lslot + (k0),        \
                (DST) + c_ * 512);                                             \
    }                                                                          \
} while (0)

#define LOAD_B(BR) do {                                                        \
    _Pragma("unroll")                                                          \
    for (int ni_ = 0; ni_ < 4; ni_++) {                                        \
        bfr[ni_][0] = *(const bf16x8*)((BR) + bBase + ni_ * 16 * BK + so0);    \
        bfr[ni_][1] = *(const bf16x8*)((BR) + bBase + ni_ * 16 * BK + so1);    \
    }                                                                          \
} while (0)

// phase q reads A rows q*64 + wm*32 + s_*16 + mlane (M-interleaved)
#define LOAD_A(AR, q) do {                                                     \
    _Pragma("unroll")                                                          \
    for (int s_ = 0; s_ < 2; s_++) {                                           \
        afr[s_][0] = *(const bf16x8*)((AR) + aBase + ((q) * 64 + s_ * 16) * BK + so0); \
        afr[s_][1] = *(const bf16x8*)((AR) + aBase + ((q) * 64 + s_ * 16) * BK + so1); \
    }                                                                          \
} while (0)

#define MFMA_PHASE(q) do {                                                     \
    __builtin_amdgcn_s_setprio(1);                                             \
    _Pragma("unroll")                                                          \
    for (int s_ = 0; s_ < 2; s_++)                                             \
    _Pragma("unroll")                                                          \
    for (int ni_ = 0; ni_ < 4; ni_++) {                                        \
        acc[(q) * 2 + s_][ni_] = __builtin_amdgcn_mfma_f32_16x16x32_bf16(      \
            afr[s_][0], bfr[ni_][0], acc[(q) * 2 + s_][ni_], 0, 0, 0);         \
        acc[(q) * 2 + s_][ni_] = __builtin_amdgcn_mfma_f32_16x16x32_bf16(      \
            afr[s_][1], bfr[ni_][1], acc[(q) * 2 + s_][ni_], 0, 0, 0);         \
    }                                                                          \
    __builtin_amdgcn_s_setprio(0);                                             \
} while (0)

// WITHB: 1 -> also load B fragments (first phase of a tile)
#define PHASE(AR, BR, q, WITHB, STAGE_STMT, TAIL_STMT) do {                    \
    if (WITHB) { LOAD_B(BR); }                                                 \
    LOAD_A(AR, q);                                                             \
    STAGE_STMT;                                                                \
    __builtin_amdgcn_sched_barrier(0);                                         \
    __builtin_amdgcn_s_barrier();                                              \
    asm volatile("s_waitcnt lgkmcnt(0)" ::: "memory");                         \
    __builtin_amdgcn_sched_barrier(0);                                         \
    MFMA_PHASE(q);                                                             \
    TAIL_STMT;                                                                 \
    __builtin_amdgcn_s_barrier();                                              \
} while (0)

#define WAIT2 asm volatile("s_waitcnt vmcnt(2)" ::: "memory")

__global__ __launch_bounds__(512, 2) void gemm_bt(
    const u16* __restrict__ Xbf,   // [32768][4096]
    const u16* __restrict__ Wbf,   // [2][4096][4096]
    const float* __restrict__ bv, const float* __restrict__ bt,
    u16* __restrict__ Ybf)         // [32768][4096]
{
    __shared__ __align__(16) u16 lds[4 * TILE_E];   // 128 KB
    u16* const As0 = lds;
    u16* const As1 = lds + TILE_E;
    u16* const Bs0 = lds + 2 * TILE_E;
    u16* const Bs1 = lds + 3 * TILE_E;

    const int tid = threadIdx.x;
    const int wave = tid >> 6, lane = tid & 63;

    // XCD swizzle: per-XCD 16 row-blocks, bm-fastest within a col-panel so the
    // 32 concurrent CUs of an XCD share ~2 B-panels (fits 4MB L2).
    const int bid = blockIdx.x;
    const int xcd = bid & 7, loc = bid >> 3;         // loc 0..255
    const int bn0 = (loc >> 4) * 256;                // 16 col-panels
    const int bm0 = (xcd * 16 + (loc & 15)) * 256;   // 128 row-blocks
    const int half = (bm0 >= B_ROWS) ? 1 : 0;        // XCDs 0-3 -> Wv, 4-7 -> Wt
    const u16* __restrict__ Apan = Xbf + (size_t)bm0 * D_DIM;
    const u16* __restrict__ Bpan = Wbf + (size_t)half * D_DIM * D_DIM
                                       + (size_t)bn0 * D_DIM;
    const float* bias = half ? bt : bv;

    // staging: chunk = 8 rows x 64 cols (1 KB); lane covers row lane>>3 of the
    // chunk at pre-swizzled col slot ((lane&7)^(lane>>3))*8 (rule 21: linear LDS
    // dest, inverse-swizzled global source, swizzled reads).
    const int lrow = lane >> 3;
    const int lslot = ((lane & 7) ^ lrow) * 8;

    // reader addressing (row&7 == mlane&7 for every fragment row)
    const int wm = wave >> 2, wn = wave & 3;
    const int mlane = lane & 15, quad = lane >> 4;
    const int lswz = lane & 7;
    const int so0 = (quad ^ lswz) * 8;               // k-slice 0 slot
    const int so1 = ((4 + quad) ^ lswz) * 8;         // k-slice 1 slot
    const int aBase = (wm * 32 + mlane) * BK;
    const int bBase = (wn * 64 + mlane) * BK;

    f32x4 acc[8][4] = {};

    // prologue: tile0 all 4 halves + buf1.A0(tile1); leave buf1.A0 in flight
    STAGE_HALF(As0, Apan, 0, 0);
    STAGE_HALF(As0, Apan, 0, 1);
    STAGE_HALF(Bs0, Bpan, 0, 0);
    STAGE_HALF(Bs0, Bpan, 0, 1);
    STAGE_HALF(As1, Apan, BK, 0);
    WAIT2;
    __builtin_amdgcn_sched_barrier(0);
    __builtin_amdgcn_s_barrier();

    for (int tt = 0; tt < NKT; tt += 2) {
        const int k1 = (tt + 1) * BK;
        const int k2 = (tt + 2) * BK;   // dummy (in-bounds of workspace) on last iter
        const int k3 = (tt + 3) * BK;
        bf16x8 bfr[4][2], afr[2][2];
        // body 0: tile tt from buf0
        PHASE(As0, Bs0, 0, 1, STAGE_HALF(As1, Apan, k1, 1), );
        PHASE(As0, Bs0, 1, 0, STAGE_HALF(Bs1, Bpan, k1, 0), );
        PHASE(As0, Bs0, 2, 0, STAGE_HALF(Bs1, Bpan, k1, 1), );
        PHASE(As0, Bs0, 3, 0, STAGE_HALF(As0, Apan, k2, 0), WAIT2);
        // body 1: tile tt+1 from buf1
        PHASE(As1, Bs1, 0, 1, STAGE_HALF(As0, Apan, k2, 1), );
        PHASE(As1, Bs1, 1, 0, STAGE_HALF(Bs0, Bpan, k2, 0), );
        PHASE(As1, Bs1, 2, 0, STAGE_HALF(Bs0, Bpan, k2, 1), );
        PHASE(As1, Bs1, 3, 0, STAGE_HALF(As1, Apan, k3, 0), WAIT2);
    }
    asm volatile("s_waitcnt vmcnt(0)" ::: "memory");   // drain tail dummy stages

    // epilogue: C/D layout col=lane&15, row=quad*4+reg; M-interleaved row map
#pragma unroll
    for (int ni = 0; ni < 4; ni++) {
        const int col = bn0 + wn * 64 + ni * 16 + mlane;
        const float bcol = bias[col];
#pragma unroll
        for (int mi = 0; mi < 8; mi++) {
            f32x4 v = acc[mi][ni];
            const int row0 = bm0 + (mi >> 1) * 64 + wm * 32 + (mi & 1) * 16 + quad * 4;
            const size_t rb = (size_t)row0 * D_DIM + col;
#pragma unroll
            for (int r = 0; r < 4; r++)
                Ybf[rb + (size_t)r * D_DIM] = (u16)f2bf(v[r] + bcol);
        }
    }
}

// ---------- sim + norm + finalize (fused): one wave = 4 img rows + 4 txt rows ----------
__global__ __launch_bounds__(256) void simproj(
    const u16* __restrict__ Ybf, const u16* __restrict__ pTbf,
    const int* __restrict__ L, float* __restrict__ out)
{
    const int tid = threadIdx.x;
    const int wave = tid >> 6, lane = tid & 63;
    const int r0 = blockIdx.x * 16 + wave * 4;       // img rows r0..r0+3
    const u16* Yi = Ybf + (size_t)r0 * D_DIM;
    const u16* Yt = Yi + (size_t)B_ROWS * D_DIM;     // matching text rows

    float acc[8][15];
#pragma unroll
    for (int r = 0; r < 8; r++)
#pragma unroll
        for (int k = 0; k < 15; k++) acc[r][k] = 0.f;

    for (int i = 0; i < 8; i++) {
        const int d0 = i * 512 + lane * 8;           // 16B/lane coalesced
        bf16x8 yv[8];
#pragma unroll
        for (int r = 0; r < 4; r++) {
            yv[r]     = *(const bf16x8*)(Yi + (size_t)r * D_DIM + d0);
            yv[4 + r] = *(const bf16x8*)(Yt + (size_t)r * D_DIM + d0);
        }
#pragma unroll
        for (int j = 0; j < 8; j++) {
            const uint4* pq = (const uint4*)(pTbf + (size_t)(d0 + j) * 16);
            const uint4 q0 = pq[0], q1 = pq[1];
            const float p[14] = { bfl(q0.x), bfh(q0.x), bfl(q0.y), bfh(q0.y),
                                  bfl(q0.z), bfh(q0.z), bfl(q0.w), bfh(q0.w),
                                  bfl(q1.x), bfh(q1.x), bfl(q1.y), bfh(q1.y),
                                  bfl(q1.z), bfh(q1.z) };
#pragma unroll
            for (int r = 0; r < 8; r++) {
                const float y = (float)yv[r][j];
                acc[r][14] += y * y;
#pragma unroll
                for (int k = 0; k < 14; k++) acc[r][k] += y * p[k];
            }
        }
    }
#pragma unroll
    for (int r = 0; r < 8; r++)
#pragma unroll
        for (int k = 0; k < 15; k++) {
            float v = acc[r][k];
            v += __shfl_xor(v, 1);  v += __shfl_xor(v, 2);  v += __shfl_xor(v, 4);
            v += __shfl_xor(v, 8);  v += __shfl_xor(v, 16); v += __shfl_xor(v, 32);
            acc[r][k] = v;
        }
    if (lane == 0) {
#pragma unroll
        for (int rr = 0; rr < 4; rr++) {
            const float iv = 1.0f / fmaxf(sqrtf(acc[rr][14]), 1e-12f);
            const float it = 1.0f / fmaxf(sqrtf(acc[4 + rr][14]), 1e-12f);
#pragma unroll
            for (int k = 0; k < 14; k++) {
                const int idx = (r0 + rr) * K_CLS + k;
                out[idx] = 0.5f * (acc[rr][k] * iv + acc[4 + rr][k] * it)
                           * (float)L[idx];
            }
        }
    }
}

// ---------- launch ----------
extern "C" void kernel_launch(void* const* d_in, const int* in_sizes, int n_in,
                              void* d_out, int out_size, void* d_ws, size_t ws_size,
                              hipStream_t stream) {
    const float* image  = (const float*)d_in[0];
    const float* text   = (const float*)d_in[1];
    const int*   labels = (const int*)d_in[2];
    const float* Wv     = (const float*)d_in[3];
    const float* bv     = (const float*)d_in[4];
    const float* Wt     = (const float*)d_in[5];
    const float* bt     = (const float*)d_in[6];
    const float* protos = (const float*)d_in[7];
    const float* cooc   = (const float*)d_in[8];
    float* out = (float*)d_out;

    // workspace layout (bytes)
    const size_t OFF_X   = 0;                       // 268,435,456  x bf16 [32768][4096]
    const size_t OFF_W   = 268435456ull;            //  67,108,864  Wv,Wt bf16
    const size_t OFF_Y   = 335544320ull;            // 268,435,456  y bf16 [32768][4096]
    const size_t OFF_PT  = 603979776ull;            //     131,072  p_hat bf16 [4096][16]
    const size_t OFF_BC  = 605945856ull;            //         784  bc f32 [196]
    const size_t NEED    = 605946640ull;
    if (ws_size < NEED) return;

    char* ws = (char*)d_ws;
    u16*   Xbf  = (u16*)(ws + OFF_X);
    u16*   Wbf  = (u16*)(ws + OFF_W);
    u16*   Ybf  = (u16*)(ws + OFF_Y);
    u16*   pTbf = (u16*)(ws + OFF_PT);
    float* bc   = (float*)(ws + OFF_BC);

    // fused casts (one launch)
    cast_all<<<4096, 256, 0, stream>>>(image, text, Wv, Wt, Xbf, Wbf);

    // small side computations
    proto_norm<<<K_CLS, 256, 0, stream>>>(protos, pTbf, out + B_ROWS * K_CLS);
    cooccur_bc<<<K_CLS * K_CLS, 256, 0, stream>>>(labels, bc);
    cooccur_loss<<<1, 256, 0, stream>>>(cooc, bc, out + B_ROWS * K_CLS + K_CLS * D_DIM);

    // main GEMM: 2048 blocks of 512 threads; 256x256 tiles over [32768][4096]
    gemm_bt<<<(M_TOT / 256) * (D_DIM / 256), 512, 0, stream>>>(Xbf, Wbf, bv, bt, Ybf);

    // projection + normalization + shapley combine (fused)
    simproj<<<B_ROWS / 16, 256, 0, stream>>>(Ybf, pTbf, labels, out);
}